// Round 8
// baseline (383.558 us; speedup 1.0000x reference)
//
#include <hip/hip_runtime.h>
#include <stdint.h>

#define DEPTHC 2
#define DIMC   512
#define FFC    2048
#define INNERC 32
#define VOCABC 8192
#define BC     2
#define LC     512
#define NTOK   1024   // B*L

typedef _Float16 f16;
typedef __attribute__((ext_vector_type(8))) _Float16 f16x8;
typedef __attribute__((ext_vector_type(4))) float f32x4;

__device__ __forceinline__ float2 cmul2(float2 a, float2 b){
    return make_float2(a.x*b.x - a.y*b.y, a.x*b.y + a.y*b.x);
}
__device__ __forceinline__ float2 cadd2(float2 a, float2 b){
    return make_float2(a.x + b.x, a.y + b.y);
}

__device__ __forceinline__ void gl_lds16(const void* g, void* l){
    __builtin_amdgcn_global_load_lds(
        (const __attribute__((address_space(1))) unsigned int*)g,
        (__attribute__((address_space(3))) unsigned int*)l, 16, 0, 0);
}

__device__ __forceinline__ void cvt8(const float* s, f16* d){
    float4 va = ((const float4*)s)[0], vb = ((const float4*)s)[1];
    union { f16 h[8]; float4 f4; } u;
    u.h[0]=(f16)va.x; u.h[1]=(f16)va.y; u.h[2]=(f16)va.z; u.h[3]=(f16)va.w;
    u.h[4]=(f16)vb.x; u.h[5]=(f16)vb.y; u.h[6]=(f16)vb.z; u.h[7]=(f16)vb.w;
    *(float4*)d = u.f4;
}

// ---------------- inverse kernel: 2 blocks, 1 wave each; register Gauss-Jordan ----------------
// ISOLATED in its own kernel so its 64+ VGPRs don't cap the convert kernel's occupancy (m69:
// waves/CU halves at VGPR=64 — this poisoned k_prep in rounds 6-7).
__global__ __launch_bounds__(64) void k_inv(
    const float* __restrict__ v_re, const float* __restrict__ v_im,
    const float* __restrict__ h0re, const float* __restrict__ h0im,
    float2* __restrict__ vinv, float2* __restrict__ h0c)
{
    const int d = blockIdx.x;
    const int c = threadIdx.x;             // lane owns column c of augmented [V | I]
    if (c < 32) h0c[d*32 + c] = make_float2(h0re[d*32 + c], h0im[d*32 + c]);
    float2 col[32];
#pragma unroll
    for (int r = 0; r < 32; ++r){
        if (c < 32) col[r] = make_float2(v_re[d*1024 + r*32 + c], v_im[d*1024 + r*32 + c]);
        else        col[r] = make_float2((c - 32) == r ? 1.f : 0.f, 0.f);
    }
#pragma unroll
    for (int k = 0; k < 32; ++k){
        float px = __shfl(col[k].x, k, 64);
        float py = __shfl(col[k].y, k, 64);
        float dm = px*px + py*py;
        float ir = px/dm, ii = -py/dm;
        float2 nv = make_float2(col[k].x*ir - col[k].y*ii, col[k].x*ii + col[k].y*ir);
        col[k] = nv;
#pragma unroll
        for (int r = 0; r < 32; ++r){
            if (r == k) continue;
            float fx = __shfl(col[r].x, k, 64);   // pivot-column entry M[r][k] (lane k)
            float fy = __shfl(col[r].y, k, 64);
            col[r].x -= fx*nv.x - fy*nv.y;
            col[r].y -= fx*nv.y + fy*nv.x;
        }
    }
    if (c >= 32){
#pragma unroll
        for (int r = 0; r < 32; ++r)
            vinv[d*1024 + r*32 + (c - 32)] = col[r];
    }
}

// ---------------- convert kernel: grid-stride fp32->f16, 8 elems/iter, lean VGPR ----------------
// chunk = 2048 elems (one block-iteration). Segment boundaries all multiples of 2048.
#define CH_X   4096   // x: 8,388,608 / 2048
#define CH_E0  (CH_X)
#define CH_E1  (CH_E0 + 2048)   // w_in
#define CH_E2  (CH_E1 + 1024)   // w1
#define CH_E3  (CH_E2 + 1024)   // w2
#define CH_E4  (CH_E3 + 2048)   // w_out
#define CH_E5  (CH_E4 + 64)     // gates
#define CONV_GRID 2048

__global__ __launch_bounds__(256) void k_conv(
    const float* __restrict__ s0, const float* __restrict__ s1,
    const float* __restrict__ s2, const float* __restrict__ s3,
    const float* __restrict__ s4,
    const float* __restrict__ wa4, const float* __restrict__ wx4,
    f16* __restrict__ d0, f16* __restrict__ d1, f16* __restrict__ d2,
    f16* __restrict__ d3, f16* __restrict__ d4, f16* __restrict__ wgb)
{
    const int tid = threadIdx.x;
    for (int c = blockIdx.x; c < CH_E5; c += CONV_GRID){
        if (c < CH_E4){
            const float* s; f16* d; size_t base;
            if (c < CH_E0)      { s = s0; d = d0; base = (size_t)c * 2048; }
            else if (c < CH_E1) { s = s1; d = d1; base = (size_t)(c - CH_E0) * 2048; }
            else if (c < CH_E2) { s = s2; d = d2; base = (size_t)(c - CH_E1) * 2048; }
            else if (c < CH_E3) { s = s3; d = d3; base = (size_t)(c - CH_E2) * 2048; }
            else                { s = s4; d = d4; base = (size_t)(c - CH_E3) * 2048; }
            size_t i = base + (size_t)tid * 8;
            cvt8(s + i, d + i);
        } else {
            // gate weights: wa[d][64][512], wx[d][64][512] -> wgb[d][128][512]
            int i = (c - CH_E4) * 2048 + tid * 8;   // [0, 131072)
            const float* gs; f16* gd;
            if (i < 65536){
                int dd = i >> 15, rem = i & 32767;
                gs = wa4 + i; gd = wgb + dd*65536 + rem;
            } else {
                int e2 = i - 65536;
                int dd = e2 >> 15, rem = e2 & 32767;
                gs = wx4 + e2; gd = wgb + dd*65536 + 32768 + rem;
            }
            cvt8(gs, gd);
        }
    }
}

// ---------------- fp16 MFMA GEMM, MTxNT tile, BK=64 ----------------
// C[M,N] = A[M,K] * B[N,K]^T. 4 waves in 2x2; wave tile (MT/2)x(NT/2).
// LDS bank-conflict fix (T2/m173): LDS layout holds column chunk (c^(row&7)) at slot c,
// via pre-swizzled global source address for global_load_lds; fragment reads apply the
// same XOR (key = l&7; wave-tile row offsets are 0 mod 8). Content bit-identical.
// MODE 0: f32 out = acc + bias[col]; MODE 1: f16 split-K partial; MODE 2: f16 silu(acc+bias)
// MODE 3: gate epilogue: pair (re,im) via shfl_xor(1); cols 0..63 -> a_t, 64..127 -> xc
template<int MT, int NT, int MODE>
__global__ __launch_bounds__(256) void k_gemmT(
    const f16* __restrict__ A, const f16* __restrict__ Bw,
    void* __restrict__ C, const float* __restrict__ bias,
    int N, int K, int klen, int partStride,
    float2* __restrict__ a_tp, float2* __restrict__ xcp)
{
    constexpr int RM = MT/32, RN = NT/32;
    __shared__ __align__(16) f16 As[MT*64];
    __shared__ __align__(16) f16 Bs[NT*64];
    const int tid = threadIdx.x;
    const int m0 = blockIdx.y * MT;
    const int n0 = blockIdx.x * NT;
    const int kbeg = blockIdx.z * klen;
    const int l = tid & 63;
    const int w = tid >> 6;
    const int fr = l & 15;
    const int fq = l >> 4;
    const int kx = l & 7;                 // swizzle key for fragment reads
    const int wm = (w >> 1) * (MT/2);
    const int wn = (w & 1) * (NT/2);
    // staging: issue i covers 32 rows; thread t -> row (t>>3); source col chunk ((t&7)^(row&7))*8
    const int srow = tid >> 3;
    const int schunk = (tid & 7) ^ (srow & 7);
    const f16* gA = A  + (size_t)(m0 + srow) * K + kbeg + schunk * 8;
    const f16* gB = Bw + (size_t)(n0 + srow) * K + kbeg + schunk * 8;
    const size_t rowskip = (size_t)32 * K;   // row+32 keeps (row&7) -> same swizzle
    f16* lA = As + tid * 8;
    f16* lB = Bs + tid * 8;
    f32x4 acc[RM][RN];
#pragma unroll
    for (int i = 0; i < RM; ++i)
#pragma unroll
        for (int j = 0; j < RN; ++j)
            acc[i][j] = (f32x4){0.f, 0.f, 0.f, 0.f};
    for (int kk = 0; kk < klen; kk += 64){
        __syncthreads();
#pragma unroll
        for (int i = 0; i < MT/32; ++i) gl_lds16(gA + i*rowskip, lA + i*2048);
#pragma unroll
        for (int i = 0; i < NT/32; ++i) gl_lds16(gB + i*rowskip, lB + i*2048);
        gA += 64; gB += 64;
        __syncthreads();
#pragma unroll
        for (int h = 0; h < 2; ++h){
            f16x8 af[RM], bf[RN];
#pragma unroll
            for (int i = 0; i < RM; ++i)
                af[i] = *(const f16x8*)(As + (wm + 16*i + fr) * 64 + (((h*4 + fq) ^ kx)) * 8);
#pragma unroll
            for (int j = 0; j < RN; ++j)
                bf[j] = *(const f16x8*)(Bs + (wn + 16*j + fr) * 64 + (((h*4 + fq) ^ kx)) * 8);
#pragma unroll
            for (int i = 0; i < RM; ++i)
#pragma unroll
                for (int j = 0; j < RN; ++j)
                    acc[i][j] = __builtin_amdgcn_mfma_f32_16x16x32_f16(af[i], bf[j], acc[i][j], 0, 0, 0);
        }
    }
#pragma unroll
    for (int i = 0; i < RM; ++i)
#pragma unroll
        for (int j = 0; j < RN; ++j)
#pragma unroll
            for (int r = 0; r < 4; ++r){
                int row = m0 + wm + 16*i + fq*4 + r;
                int col = n0 + wn + 16*j + fr;
                if (MODE == 1){
                    ((f16*)C + (size_t)blockIdx.z * partStride)[(size_t)row * N + col] = (f16)acc[i][j][r];
                } else if (MODE == 0){
                    ((float*)C)[(size_t)row * N + col] = acc[i][j][r] + bias[col];
                } else if (MODE == 2){
                    float v = acc[i][j][r] + bias[col];
                    ((f16*)C)[(size_t)row * N + col] = (f16)(v / (1.f + __expf(-v)));
                } else {
                    // MODE 3: gate nonlinearity; even col = re, odd col = im
                    float val = acc[i][j][r];
                    float pv = __shfl_xor(val, 1, 64);
                    if (!(fr & 1)){
                        float re = val, im = pv;
                        int bb = row >> 9, t = row & 511;
                        float m2 = re*re + im*im;
                        if (col < 64){
                            int k = col >> 1;
                            float sa = rsqrtf(m2) * (m2 / (1.f + m2));
                            a_tp[(size_t)(bb*INNERC + k)*LC + t] = make_float2(re*sa, im*sa);
                        } else {
                            int k = (col - 64) >> 1;
                            float sx = sqrtf(m2);
                            xcp[(size_t)row*INNERC + k] = make_float2(re*sx, im*sx);
                        }
                    }
                }
            }
}

// ---------------- split-K reduce + residual + LayerNorm -> f16 z; optional f32 h out ----------
__global__ __launch_bounds__(128) void k_ln1(
    const f16* __restrict__ part, const float* __restrict__ bias,
    const float* __restrict__ res, const float* __restrict__ g,
    const float* __restrict__ b, f16* __restrict__ out,
    float* __restrict__ hout, int n)
{
    int row = blockIdx.x;
    int tid = threadIdx.x;
    __shared__ float sw[2], qw[2];
    float v[4]; float s = 0.f, q = 0.f;
#pragma unroll
    for (int j = 0; j < 4; ++j){
        int c = tid + 128*j;
        int idx = row*DIMC + c;
        float t = bias[c];
        if (res) t += res[idx];
#pragma unroll
        for (int z = 0; z < 8; ++z) t += (float)part[(size_t)z * n + idx];
        if (hout) hout[idx] = t;
        v[j] = t; s += t; q += t*t;
    }
    for (int off = 32; off; off >>= 1){ s += __shfl_down(s, off, 64); q += __shfl_down(q, off, 64); }
    if ((tid & 63) == 0){ sw[tid >> 6] = s; qw[tid >> 6] = q; }
    __syncthreads();
    float S = sw[0] + sw[1], Q = qw[0] + qw[1];
    float m = S / DIMC;
    float rstd = rsqrtf(Q / DIMC - m*m + 1e-5f);
#pragma unroll
    for (int j = 0; j < 4; ++j){
        int c = tid + 128*j;
        out[(size_t)row*DIMC + c] = (f16)((v[j] - m)*rstd*g[c] + b[c]);
    }
}

// ---------------- fused wprime + scan: e[t] = a[t]*(e[t-1] + Vinv@xroll[t]) ----------------
__global__ __launch_bounds__(64) void k_scan(
    const float2* __restrict__ a_t, const float2* __restrict__ xc,
    const float2* __restrict__ vinv, const float2* __restrict__ h0c,
    float2* __restrict__ e)
{
    int bk = blockIdx.x;   // b*32 + k
    int l = threadIdx.x;   // 0..63, each owns 8 consecutive t
    int bb = bk >> 5, k = bk & 31;
    float2 vrow[32];
#pragma unroll
    for (int o = 0; o < 32; ++o) vrow[o] = vinv[k*32 + o];
    int base = bk * LC + l * 8;
    float2 av[8], wv[8];
#pragma unroll
    for (int j = 0; j < 8; ++j) av[j] = a_t[base + j];
#pragma unroll
    for (int j = 0; j < 8; ++j){
        int t = l*8 + j;
        const float2* src = (t == 0) ? h0c : (xc + (size_t)(bb*LC + t - 1) * INNERC);
        float2 acc = make_float2(0.f, 0.f);
#pragma unroll
        for (int o = 0; o < 32; o += 2){
            float4 qq = *(const float4*)(src + o);
            acc.x += vrow[o].x*qq.x - vrow[o].y*qq.y;
            acc.y += vrow[o].x*qq.y + vrow[o].y*qq.x;
            acc.x += vrow[o+1].x*qq.z - vrow[o+1].y*qq.w;
            acc.y += vrow[o+1].x*qq.w + vrow[o+1].y*qq.z;
        }
        wv[j] = acc;
    }
    float2 A = make_float2(1.f, 0.f), Bc = make_float2(0.f, 0.f);
#pragma unroll
    for (int j = 0; j < 8; ++j){
        Bc = cmul2(av[j], cadd2(Bc, wv[j]));
        A  = cmul2(av[j], A);
    }
    for (int off = 1; off < 64; off <<= 1){
        float Apx = __shfl_up(A.x,  off, 64), Apy = __shfl_up(A.y,  off, 64);
        float Bpx = __shfl_up(Bc.x, off, 64), Bpy = __shfl_up(Bc.y, off, 64);
        if (l >= off){
            float2 Ap = make_float2(Apx, Apy), Bp = make_float2(Bpx, Bpy);
            Bc = cadd2(cmul2(A, Bp), Bc);
            A  = cmul2(A, Ap);
        }
    }
    float ex = __shfl_up(Bc.x, 1, 64), ey = __shfl_up(Bc.y, 1, 64);
    float2 ecur = (l == 0) ? make_float2(0.f, 0.f) : make_float2(ex, ey);
    size_t obase = ((size_t)bb*LC + l*8) * INNERC + k;
#pragma unroll
    for (int j = 0; j < 8; ++j){
        ecur = cmul2(av[j], cadd2(ecur, wv[j]));
        e[obase + (size_t)j * INNERC] = ecur;
    }
}

// ---------------- hr = Re(V*e)+Re(xc); val = hr@w_ol^T + res; hout=val; zout=LN2(val) f16 ----------------
__global__ __launch_bounds__(128) void k_siout_ln(
    const float2* __restrict__ e, const float2* __restrict__ xc,
    const float* __restrict__ vre, const float* __restrict__ vim,
    const float* __restrict__ wol, const float* __restrict__ res,
    const float* __restrict__ g2, const float* __restrict__ b2,
    float* __restrict__ hout, f16* __restrict__ zout)
{
    int bt = blockIdx.x;
    int tid = threadIdx.x;
    __shared__ float hr[INNERC];
    __shared__ float2 er[INNERC];
    __shared__ float sw[2], qw[2];
    if (tid < 32) er[tid] = e[(size_t)bt*INNERC + tid];
    __syncthreads();
    if (tid < 32){
        const float* vrr = vre + tid*INNERC;
        const float* vir = vim + tid*INNERC;
        float acc = xc[(size_t)bt*INNERC + tid].x;
#pragma unroll
        for (int k2 = 0; k2 < 32; ++k2) acc += vrr[k2]*er[k2].x - vir[k2]*er[k2].y;
        hr[tid] = acc;
    }
    __syncthreads();
    float v[4]; float s = 0.f, q = 0.f;
#pragma unroll
    for (int j = 0; j < 4; ++j){
        int n = tid + 128*j;
        float val = res[(size_t)bt*DIMC + n];
        const float* wr = wol + (size_t)n * INNERC;
#pragma unroll
        for (int i = 0; i < 32; ++i) val += hr[i]*wr[i];
        hout[(size_t)bt*DIMC + n] = val;
        v[j] = val; s += val; q += val*val;
    }
    for (int off = 32; off; off >>= 1){ s += __shfl_down(s, off, 64); q += __shfl_down(q, off, 64); }
    if ((tid & 63) == 0){ sw[tid >> 6] = s; qw[tid >> 6] = q; }
    __syncthreads();
    float S = sw[0] + sw[1], Q = qw[0] + qw[1];
    float m = S / DIMC;
    float rstd = rsqrtf(Q / DIMC - m*m + 1e-5f);
#pragma unroll
    for (int j = 0; j < 4; ++j){
        int n = tid + 128*j;
        zout[(size_t)bt*DIMC + n] = (f16)((v[j] - m)*rstd*g2[n] + b2[n]);
    }
}

extern "C" void kernel_launch(void* const* d_in, const int* in_sizes, int n_in,
                              void* d_out, int out_size, void* d_ws, size_t ws_size,
                              hipStream_t stream)
{
    const float* x     = (const float*)d_in[0];
    const float* w_in  = (const float*)d_in[1];
    const float* b_in  = (const float*)d_in[2];
    const float* ln1_g = (const float*)d_in[3];
    const float* ln1_b = (const float*)d_in[4];
    const float* wa    = (const float*)d_in[5];
    const float* wx    = (const float*)d_in[6];
    const float* v_re  = (const float*)d_in[7];
    const float* v_im  = (const float*)d_in[8];
    const float* h0_re = (const float*)d_in[9];
    const float* h0_im = (const float*)d_in[10];
    const float* w_ol  = (const float*)d_in[11];
    const float* ln2_g = (const float*)d_in[12];
    const float* ln2_b = (const float*)d_in[13];
    const float* w1    = (const float*)d_in[14];
    const float* b1    = (const float*)d_in[15];
    const float* w2    = (const float*)d_in[16];
    const float* b2    = (const float*)d_in[17];
    const float* lnl_g = (const float*)d_in[18];
    const float* lnl_b = (const float*)d_in[19];
    const float* w_out = (const float*)d_in[20];
    const float* b_out = (const float*)d_in[21];

    char* p = (char*)d_ws;
    f16* xb   = (f16*)p;   p += (size_t)NTOK * VOCABC * 2;
    f16* wib  = (f16*)p;   p += (size_t)DIMC * VOCABC * 2;
    f16* wob  = (f16*)p;   p += (size_t)VOCABC * DIMC * 2;
    f16* w1b  = (f16*)p;   p += (size_t)DEPTHC * FFC * DIMC * 2;
    f16* w2b  = (f16*)p;   p += (size_t)DEPTHC * DIMC * FFC * 2;
    f16* wgb  = (f16*)p;   p += (size_t)DEPTHC * 2*INNERC*2 * DIMC * 2;  // [d][128][512] f16
    float* h1 = (float*)p; p += (size_t)NTOK * DIMC * 4;
    float* h2 = (float*)p; p += (size_t)NTOK * DIMC * 4;
    float* h3 = (float*)p; p += (size_t)NTOK * DIMC * 4;
    f16* zb   = (f16*)p;   p += (size_t)NTOK * DIMC * 2;
    f16* ffb  = (f16*)p;   p += (size_t)NTOK * FFC * 2;
    f16* pbuf = (f16*)p;   p += (size_t)8 * NTOK * DIMC * 2;
    float2* a_t = (float2*)p; p += (size_t)BC * INNERC * LC * 8;
    float2* xc  = (float2*)p; p += (size_t)NTOK * INNERC * 8;
    float2* ev  = (float2*)p; p += (size_t)NTOK * INNERC * 8;
    float2* vinv = (float2*)p; p += (size_t)DEPTHC * INNERC * INNERC * 8;
    float2* h0c  = (float2*)p; p += (size_t)DEPTHC * INNERC * 8;

    // inverse (tiny, isolated VGPR budget) + grid-stride converts
    k_inv<<<2, 64, 0, stream>>>(v_re, v_im, h0_re, h0_im, vinv, h0c);
    k_conv<<<CONV_GRID, 256, 0, stream>>>(x, w_in, w1, w2, w_out, wa, wx,
                                          xb, wib, w1b, w2b, wob, wgb);

    // in-proj: xb(f16) @ w_in^T (64x128 tile, split-K=8, f16 partials) — 512 blocks
    {
        dim3 g(DIMC/128, NTOK/64, 8);
        k_gemmT<64,128,1><<<g, 256, 0, stream>>>(xb, wib, pbuf, nullptr, DIMC, VOCABC, VOCABC/8, NTOK*DIMC,
                                                 nullptr, nullptr);
    }

    for (int d = 0; d < DEPTHC; ++d){
        float* cur = (d == 0) ? h1 : h3;   // layer input (reduced), residual for siout
        float* hb  = h2;                    // sio+residual out
        const float* redBias = (d == 0) ? b_in : (b2 + (d-1)*DIMC);
        const float* redRes  = (d == 0) ? nullptr : h2;
        // fused: split-K reduce + residual + write h + LN1 -> z (f16)
        k_ln1<<<NTOK, 128, 0, stream>>>(pbuf, redBias, redRes,
                                        ln1_g + d*DIMC, ln1_b + d*DIMC, zb, cur, NTOK*DIMC);
        // gate projections via MFMA + fused nonlinearity -> a_t, xc  (grid 32 blocks)
        {
            dim3 g(1, NTOK/32, 1);
            k_gemmT<32,128,3><<<g, 256, 0, stream>>>(zb, wgb + (size_t)d*128*DIMC, nullptr, nullptr,
                                                     128, DIMC, DIMC, 0, a_t, xc);
        }
        k_scan<<<BC*INNERC, 64, 0, stream>>>(a_t, xc, vinv + d*INNERC*INNERC, h0c + d*INNERC, ev);
        k_siout_ln<<<NTOK, 128, 0, stream>>>(ev, xc, v_re + d*INNERC*INNERC, v_im + d*INNERC*INNERC,
                                             w_ol + (size_t)d*DIMC*INNERC, cur,
                                             ln2_g + d*DIMC, ln2_b + d*DIMC, hb, zb);
        // FFN1: 64x128 tile, silu fused, f16 out
        {
            dim3 g(FFC/128, NTOK/64, 1);
            k_gemmT<64,128,2><<<g, 256, 0, stream>>>(zb, w1b + (size_t)d*FFC*DIMC, ffb, b1 + d*FFC,
                                                     FFC, DIMC, DIMC, 0, nullptr, nullptr);
        }
        // FFN2: 64x128 tile, split-K=8, f16 partials
        {
            dim3 g(DIMC/128, NTOK/64, 8);
            k_gemmT<64,128,1><<<g, 256, 0, stream>>>(ffb, w2b + (size_t)d*DIMC*FFC, pbuf, nullptr,
                                                     DIMC, FFC, FFC/8, NTOK*DIMC, nullptr, nullptr);
        }
    }
    // final: reduce + residual + LN -> zb (f16)
    k_ln1<<<NTOK, 128, 0, stream>>>(pbuf, b2 + (DEPTHC-1)*DIMC, h2, lnl_g, lnl_b, zb, nullptr, NTOK*DIMC);
    // out = zb @ w_out^T + b_out  (128x128 tile)
    {
        dim3 g(VOCABC/128, NTOK/128, 1);
        k_gemmT<128,128,0><<<g, 256, 0, stream>>>(zb, wob, (float*)d_out, b_out, VOCABC, DIMC, DIMC, 0,
                                                  nullptr, nullptr);
    }
    (void)in_sizes; (void)n_in; (void)out_size; (void)ws_size;
}

// Round 9
// 329.006 us; speedup vs baseline: 1.1658x; 1.1658x over previous
//
#include <hip/hip_runtime.h>
#include <stdint.h>

#define DEPTHC 2
#define DIMC   512
#define FFC    2048
#define INNERC 32
#define VOCABC 8192
#define BC     2
#define LC     512
#define NTOK   1024   // B*L

typedef _Float16 f16;
typedef __attribute__((ext_vector_type(8))) _Float16 f16x8;
typedef __attribute__((ext_vector_type(4))) float f32x4;

__device__ __forceinline__ float2 cmul2(float2 a, float2 b){
    return make_float2(a.x*b.x - a.y*b.y, a.x*b.y + a.y*b.x);
}
__device__ __forceinline__ float2 cadd2(float2 a, float2 b){
    return make_float2(a.x + b.x, a.y + b.y);
}

__device__ __forceinline__ void gl_lds16(const void* g, void* l){
    __builtin_amdgcn_global_load_lds(
        (const __attribute__((address_space(1))) unsigned int*)g,
        (__attribute__((address_space(3))) unsigned int*)l, 16, 0, 0);
}

__device__ __forceinline__ void cvt8(const float* s, f16* d){
    float4 va = ((const float4*)s)[0], vb = ((const float4*)s)[1];
    union { f16 h[8]; float4 f4; } u;
    u.h[0]=(f16)va.x; u.h[1]=(f16)va.y; u.h[2]=(f16)va.z; u.h[3]=(f16)va.w;
    u.h[4]=(f16)vb.x; u.h[5]=(f16)vb.y; u.h[6]=(f16)vb.z; u.h[7]=(f16)vb.w;
    *(float4*)d = u.f4;
}

// ---------------- prep: blocks 0..1 = LDS Gauss-Jordan inverse (20 VGPR, r3/r4-proven);
// blocks 2.. = grid-stride fp32->f16 converts (8 elems/iter, lean VGPR) ----------------
// Inverse hides under the converts; LDS 16KB doesn't cap occupancy (32-wave cap binds first).
#define CH_X   4096   // x: 8,388,608 / 2048
#define CH_E0  (CH_X)
#define CH_E1  (CH_E0 + 2048)   // w_in
#define CH_E2  (CH_E1 + 1024)   // w1
#define CH_E3  (CH_E2 + 1024)   // w2
#define CH_E4  (CH_E3 + 2048)   // w_out
#define CH_E5  (CH_E4 + 64)     // gates
#define CONV_GRID 2048
#define PREP_BLOCKS (CONV_GRID + 2)

__global__ __launch_bounds__(256) void k_prep(
    const float* __restrict__ s0, const float* __restrict__ s1,
    const float* __restrict__ s2, const float* __restrict__ s3,
    const float* __restrict__ s4,
    const float* __restrict__ wa4, const float* __restrict__ wx4,
    f16* __restrict__ d0, f16* __restrict__ d1, f16* __restrict__ d2,
    f16* __restrict__ d3, f16* __restrict__ d4, f16* __restrict__ wgb,
    const float* __restrict__ v_re, const float* __restrict__ v_im,
    const float* __restrict__ h0re, const float* __restrict__ h0im,
    float2* __restrict__ vinv, float2* __restrict__ h0c)
{
    __shared__ float2 M[32][64];
    if (blockIdx.x < 2){
        const int d = blockIdx.x;
        const int tid = threadIdx.x;
        const int c = tid & 63;
        const int wv = tid >> 6;             // 4 waves, rows 8wv..8wv+7
        if (tid < 32) h0c[d*32 + tid] = make_float2(h0re[d*32 + tid], h0im[d*32 + tid]);
#pragma unroll
        for (int rr = 0; rr < 8; ++rr){
            int r = wv*8 + rr;
            float re, im;
            if (c < 32){ re = v_re[d*1024 + r*32 + c]; im = v_im[d*1024 + r*32 + c]; }
            else       { re = (c - 32 == r) ? 1.f : 0.f; im = 0.f; }
            M[r][c] = make_float2(re, im);
        }
        __syncthreads();
#pragma unroll 1
        for (int col = 0; col < 32; ++col){
            float2 prow = M[col][c];                 // pivot row, own column
            float pvx = __shfl(prow.x, col, 64);
            float pvy = __shfl(prow.y, col, 64);
            float dm = pvx*pvx + pvy*pvy;
            float ir = pvx/dm, ii = -pvy/dm;
            float2 nv = make_float2(prow.x*ir - prow.y*ii, prow.x*ii + prow.y*ir);
#pragma unroll
            for (int rr = 0; rr < 8; ++rr){
                int r = wv*8 + rr;
                if (r == col) continue;
                float2 f  = M[r][col];
                float2 m0 = M[r][c];
                m0.x -= f.x*nv.x - f.y*nv.y;
                m0.y -= f.x*nv.y + f.y*nv.x;
                M[r][c] = m0;
            }
            __syncthreads();
        }
        if (c >= 32){
#pragma unroll
            for (int rr = 0; rr < 8; ++rr){
                int r = wv*8 + rr;
                float2 dv = M[r][r];
                float dm = dv.x*dv.x + dv.y*dv.y;
                float ir = dv.x/dm, ii = -dv.y/dm;
                float2 m0 = M[r][c];
                vinv[d*1024 + r*32 + (c - 32)] =
                    make_float2(m0.x*ir - m0.y*ii, m0.x*ii + m0.y*ir);
            }
        }
        return;
    }
    const int tid = threadIdx.x;
    for (int c = blockIdx.x - 2; c < CH_E5; c += CONV_GRID){
        if (c < CH_E4){
            const float* s; f16* d; size_t base;
            if (c < CH_E0)      { s = s0; d = d0; base = (size_t)c * 2048; }
            else if (c < CH_E1) { s = s1; d = d1; base = (size_t)(c - CH_E0) * 2048; }
            else if (c < CH_E2) { s = s2; d = d2; base = (size_t)(c - CH_E1) * 2048; }
            else if (c < CH_E3) { s = s3; d = d3; base = (size_t)(c - CH_E2) * 2048; }
            else                { s = s4; d = d4; base = (size_t)(c - CH_E3) * 2048; }
            size_t i = base + (size_t)tid * 8;
            cvt8(s + i, d + i);
        } else {
            // gate weights: wa[d][64][512], wx[d][64][512] -> wgb[d][128][512]
            int i = (c - CH_E4) * 2048 + tid * 8;   // [0, 131072)
            const float* gs; f16* gd;
            if (i < 65536){
                int dd = i >> 15, rem = i & 32767;
                gs = wa4 + i; gd = wgb + dd*65536 + rem;
            } else {
                int e2 = i - 65536;
                int dd = e2 >> 15, rem = e2 & 32767;
                gs = wx4 + e2; gd = wgb + dd*65536 + 32768 + rem;
            }
            cvt8(gs, gd);
        }
    }
}

// ---------------- fp16 MFMA GEMM, MTxNT tile, BK=64 ----------------
// C[M,N] = A[M,K] * B[N,K]^T. 4 waves in 2x2; wave tile (MT/2)x(NT/2).
// LDS bank-conflict fix (T2/m173): LDS layout holds column chunk (c^(row&7)) at slot c,
// via pre-swizzled global source address for global_load_lds; fragment reads apply the
// same XOR (key = l&7; wave-tile row offsets are 0 mod 8). Content bit-identical.
// MODE 0: f32 out = acc + bias[col]; MODE 1: f16 split-K partial; MODE 2: f16 silu(acc+bias)
// MODE 3: gate epilogue: pair (re,im) via shfl_xor(1); cols 0..63 -> a_t, 64..127 -> xc
template<int MT, int NT, int MODE>
__global__ __launch_bounds__(256) void k_gemmT(
    const f16* __restrict__ A, const f16* __restrict__ Bw,
    void* __restrict__ C, const float* __restrict__ bias,
    int N, int K, int klen, int partStride,
    float2* __restrict__ a_tp, float2* __restrict__ xcp)
{
    constexpr int RM = MT/32, RN = NT/32;
    __shared__ __align__(16) f16 As[MT*64];
    __shared__ __align__(16) f16 Bs[NT*64];
    const int tid = threadIdx.x;
    const int m0 = blockIdx.y * MT;
    const int n0 = blockIdx.x * NT;
    const int kbeg = blockIdx.z * klen;
    const int l = tid & 63;
    const int w = tid >> 6;
    const int fr = l & 15;
    const int fq = l >> 4;
    const int kx = l & 7;                 // swizzle key for fragment reads
    const int wm = (w >> 1) * (MT/2);
    const int wn = (w & 1) * (NT/2);
    // staging: issue i covers 32 rows; thread t -> row (t>>3); source col chunk ((t&7)^(row&7))*8
    const int srow = tid >> 3;
    const int schunk = (tid & 7) ^ (srow & 7);
    const f16* gA = A  + (size_t)(m0 + srow) * K + kbeg + schunk * 8;
    const f16* gB = Bw + (size_t)(n0 + srow) * K + kbeg + schunk * 8;
    const size_t rowskip = (size_t)32 * K;   // row+32 keeps (row&7) -> same swizzle
    f16* lA = As + tid * 8;
    f16* lB = Bs + tid * 8;
    f32x4 acc[RM][RN];
#pragma unroll
    for (int i = 0; i < RM; ++i)
#pragma unroll
        for (int j = 0; j < RN; ++j)
            acc[i][j] = (f32x4){0.f, 0.f, 0.f, 0.f};
    for (int kk = 0; kk < klen; kk += 64){
        __syncthreads();
#pragma unroll
        for (int i = 0; i < MT/32; ++i) gl_lds16(gA + i*rowskip, lA + i*2048);
#pragma unroll
        for (int i = 0; i < NT/32; ++i) gl_lds16(gB + i*rowskip, lB + i*2048);
        gA += 64; gB += 64;
        __syncthreads();
#pragma unroll
        for (int h = 0; h < 2; ++h){
            f16x8 af[RM], bf[RN];
#pragma unroll
            for (int i = 0; i < RM; ++i)
                af[i] = *(const f16x8*)(As + (wm + 16*i + fr) * 64 + (((h*4 + fq) ^ kx)) * 8);
#pragma unroll
            for (int j = 0; j < RN; ++j)
                bf[j] = *(const f16x8*)(Bs + (wn + 16*j + fr) * 64 + (((h*4 + fq) ^ kx)) * 8);
#pragma unroll
            for (int i = 0; i < RM; ++i)
#pragma unroll
                for (int j = 0; j < RN; ++j)
                    acc[i][j] = __builtin_amdgcn_mfma_f32_16x16x32_f16(af[i], bf[j], acc[i][j], 0, 0, 0);
        }
    }
#pragma unroll
    for (int i = 0; i < RM; ++i)
#pragma unroll
        for (int j = 0; j < RN; ++j)
#pragma unroll
            for (int r = 0; r < 4; ++r){
                int row = m0 + wm + 16*i + fq*4 + r;
                int col = n0 + wn + 16*j + fr;
                if (MODE == 1){
                    ((f16*)C + (size_t)blockIdx.z * partStride)[(size_t)row * N + col] = (f16)acc[i][j][r];
                } else if (MODE == 0){
                    ((float*)C)[(size_t)row * N + col] = acc[i][j][r] + bias[col];
                } else if (MODE == 2){
                    float v = acc[i][j][r] + bias[col];
                    ((f16*)C)[(size_t)row * N + col] = (f16)(v / (1.f + __expf(-v)));
                } else {
                    // MODE 3: gate nonlinearity; even col = re, odd col = im
                    float val = acc[i][j][r];
                    float pv = __shfl_xor(val, 1, 64);
                    if (!(fr & 1)){
                        float re = val, im = pv;
                        int bb = row >> 9, t = row & 511;
                        float m2 = re*re + im*im;
                        if (col < 64){
                            int k = col >> 1;
                            float sa = rsqrtf(m2) * (m2 / (1.f + m2));
                            a_tp[(size_t)(bb*INNERC + k)*LC + t] = make_float2(re*sa, im*sa);
                        } else {
                            int k = (col - 64) >> 1;
                            float sx = sqrtf(m2);
                            xcp[(size_t)row*INNERC + k] = make_float2(re*sx, im*sx);
                        }
                    }
                }
            }
}

// ---------------- split-K reduce + residual + LayerNorm -> f16 z; optional f32 h out ----------
__global__ __launch_bounds__(128) void k_ln1(
    const f16* __restrict__ part, const float* __restrict__ bias,
    const float* __restrict__ res, const float* __restrict__ g,
    const float* __restrict__ b, f16* __restrict__ out,
    float* __restrict__ hout, int n)
{
    int row = blockIdx.x;
    int tid = threadIdx.x;
    __shared__ float sw[2], qw[2];
    float v[4]; float s = 0.f, q = 0.f;
#pragma unroll
    for (int j = 0; j < 4; ++j){
        int c = tid + 128*j;
        int idx = row*DIMC + c;
        float t = bias[c];
        if (res) t += res[idx];
#pragma unroll
        for (int z = 0; z < 8; ++z) t += (float)part[(size_t)z * n + idx];
        if (hout) hout[idx] = t;
        v[j] = t; s += t; q += t*t;
    }
    for (int off = 32; off; off >>= 1){ s += __shfl_down(s, off, 64); q += __shfl_down(q, off, 64); }
    if ((tid & 63) == 0){ sw[tid >> 6] = s; qw[tid >> 6] = q; }
    __syncthreads();
    float S = sw[0] + sw[1], Q = qw[0] + qw[1];
    float m = S / DIMC;
    float rstd = rsqrtf(Q / DIMC - m*m + 1e-5f);
#pragma unroll
    for (int j = 0; j < 4; ++j){
        int c = tid + 128*j;
        out[(size_t)row*DIMC + c] = (f16)((v[j] - m)*rstd*g[c] + b[c]);
    }
}

// ---------------- fused wprime + scan: e[t] = a[t]*(e[t-1] + Vinv@xroll[t]) ----------------
__global__ __launch_bounds__(64) void k_scan(
    const float2* __restrict__ a_t, const float2* __restrict__ xc,
    const float2* __restrict__ vinv, const float2* __restrict__ h0c,
    float2* __restrict__ e)
{
    int bk = blockIdx.x;   // b*32 + k
    int l = threadIdx.x;   // 0..63, each owns 8 consecutive t
    int bb = bk >> 5, k = bk & 31;
    float2 vrow[32];
#pragma unroll
    for (int o = 0; o < 32; ++o) vrow[o] = vinv[k*32 + o];
    int base = bk * LC + l * 8;
    float2 av[8], wv[8];
#pragma unroll
    for (int j = 0; j < 8; ++j) av[j] = a_t[base + j];
#pragma unroll
    for (int j = 0; j < 8; ++j){
        int t = l*8 + j;
        const float2* src = (t == 0) ? h0c : (xc + (size_t)(bb*LC + t - 1) * INNERC);
        float2 acc = make_float2(0.f, 0.f);
#pragma unroll
        for (int o = 0; o < 32; o += 2){
            float4 qq = *(const float4*)(src + o);
            acc.x += vrow[o].x*qq.x - vrow[o].y*qq.y;
            acc.y += vrow[o].x*qq.y + vrow[o].y*qq.x;
            acc.x += vrow[o+1].x*qq.z - vrow[o+1].y*qq.w;
            acc.y += vrow[o+1].x*qq.w + vrow[o+1].y*qq.z;
        }
        wv[j] = acc;
    }
    float2 A = make_float2(1.f, 0.f), Bc = make_float2(0.f, 0.f);
#pragma unroll
    for (int j = 0; j < 8; ++j){
        Bc = cmul2(av[j], cadd2(Bc, wv[j]));
        A  = cmul2(av[j], A);
    }
    for (int off = 1; off < 64; off <<= 1){
        float Apx = __shfl_up(A.x,  off, 64), Apy = __shfl_up(A.y,  off, 64);
        float Bpx = __shfl_up(Bc.x, off, 64), Bpy = __shfl_up(Bc.y, off, 64);
        if (l >= off){
            float2 Ap = make_float2(Apx, Apy), Bp = make_float2(Bpx, Bpy);
            Bc = cadd2(cmul2(A, Bp), Bc);
            A  = cmul2(A, Ap);
        }
    }
    float ex = __shfl_up(Bc.x, 1, 64), ey = __shfl_up(Bc.y, 1, 64);
    float2 ecur = (l == 0) ? make_float2(0.f, 0.f) : make_float2(ex, ey);
    size_t obase = ((size_t)bb*LC + l*8) * INNERC + k;
#pragma unroll
    for (int j = 0; j < 8; ++j){
        ecur = cmul2(av[j], cadd2(ecur, wv[j]));
        e[obase + (size_t)j * INNERC] = ecur;
    }
}

// ---------------- hr = Re(V*e)+Re(xc); val = hr@w_ol^T + res; hout=val; zout=LN2(val) f16 ----------------
__global__ __launch_bounds__(128) void k_siout_ln(
    const float2* __restrict__ e, const float2* __restrict__ xc,
    const float* __restrict__ vre, const float* __restrict__ vim,
    const float* __restrict__ wol, const float* __restrict__ res,
    const float* __restrict__ g2, const float* __restrict__ b2,
    float* __restrict__ hout, f16* __restrict__ zout)
{
    int bt = blockIdx.x;
    int tid = threadIdx.x;
    __shared__ float hr[INNERC];
    __shared__ float2 er[INNERC];
    __shared__ float sw[2], qw[2];
    if (tid < 32) er[tid] = e[(size_t)bt*INNERC + tid];
    __syncthreads();
    if (tid < 32){
        const float* vrr = vre + tid*INNERC;
        const float* vir = vim + tid*INNERC;
        float acc = xc[(size_t)bt*INNERC + tid].x;
#pragma unroll
        for (int k2 = 0; k2 < 32; ++k2) acc += vrr[k2]*er[k2].x - vir[k2]*er[k2].y;
        hr[tid] = acc;
    }
    __syncthreads();
    float v[4]; float s = 0.f, q = 0.f;
#pragma unroll
    for (int j = 0; j < 4; ++j){
        int n = tid + 128*j;
        float val = res[(size_t)bt*DIMC + n];
        const float* wr = wol + (size_t)n * INNERC;
#pragma unroll
        for (int i = 0; i < 32; ++i) val += hr[i]*wr[i];
        hout[(size_t)bt*DIMC + n] = val;
        v[j] = val; s += val; q += val*val;
    }
    for (int off = 32; off; off >>= 1){ s += __shfl_down(s, off, 64); q += __shfl_down(q, off, 64); }
    if ((tid & 63) == 0){ sw[tid >> 6] = s; qw[tid >> 6] = q; }
    __syncthreads();
    float S = sw[0] + sw[1], Q = qw[0] + qw[1];
    float m = S / DIMC;
    float rstd = rsqrtf(Q / DIMC - m*m + 1e-5f);
#pragma unroll
    for (int j = 0; j < 4; ++j){
        int n = tid + 128*j;
        zout[(size_t)bt*DIMC + n] = (f16)((v[j] - m)*rstd*g2[n] + b2[n]);
    }
}

extern "C" void kernel_launch(void* const* d_in, const int* in_sizes, int n_in,
                              void* d_out, int out_size, void* d_ws, size_t ws_size,
                              hipStream_t stream)
{
    const float* x     = (const float*)d_in[0];
    const float* w_in  = (const float*)d_in[1];
    const float* b_in  = (const float*)d_in[2];
    const float* ln1_g = (const float*)d_in[3];
    const float* ln1_b = (const float*)d_in[4];
    const float* wa    = (const float*)d_in[5];
    const float* wx    = (const float*)d_in[6];
    const float* v_re  = (const float*)d_in[7];
    const float* v_im  = (const float*)d_in[8];
    const float* h0_re = (const float*)d_in[9];
    const float* h0_im = (const float*)d_in[10];
    const float* w_ol  = (const float*)d_in[11];
    const float* ln2_g = (const float*)d_in[12];
    const float* ln2_b = (const float*)d_in[13];
    const float* w1    = (const float*)d_in[14];
    const float* b1    = (const float*)d_in[15];
    const float* w2    = (const float*)d_in[16];
    const float* b2    = (const float*)d_in[17];
    const float* lnl_g = (const float*)d_in[18];
    const float* lnl_b = (const float*)d_in[19];
    const float* w_out = (const float*)d_in[20];
    const float* b_out = (const float*)d_in[21];

    char* p = (char*)d_ws;
    f16* xb   = (f16*)p;   p += (size_t)NTOK * VOCABC * 2;
    f16* wib  = (f16*)p;   p += (size_t)DIMC * VOCABC * 2;
    f16* wob  = (f16*)p;   p += (size_t)VOCABC * DIMC * 2;
    f16* w1b  = (f16*)p;   p += (size_t)DEPTHC * FFC * DIMC * 2;
    f16* w2b  = (f16*)p;   p += (size_t)DEPTHC * DIMC * FFC * 2;
    f16* wgb  = (f16*)p;   p += (size_t)DEPTHC * 2*INNERC*2 * DIMC * 2;  // [d][128][512] f16
    float* h1 = (float*)p; p += (size_t)NTOK * DIMC * 4;
    float* h2 = (float*)p; p += (size_t)NTOK * DIMC * 4;
    float* h3 = (float*)p; p += (size_t)NTOK * DIMC * 4;
    f16* zb   = (f16*)p;   p += (size_t)NTOK * DIMC * 2;
    f16* ffb  = (f16*)p;   p += (size_t)NTOK * FFC * 2;
    f16* pbuf = (f16*)p;   p += (size_t)8 * NTOK * DIMC * 2;
    float2* a_t = (float2*)p; p += (size_t)BC * INNERC * LC * 8;
    float2* xc  = (float2*)p; p += (size_t)NTOK * INNERC * 8;
    float2* ev  = (float2*)p; p += (size_t)NTOK * INNERC * 8;
    float2* vinv = (float2*)p; p += (size_t)DEPTHC * INNERC * INNERC * 8;
    float2* h0c  = (float2*)p; p += (size_t)DEPTHC * INNERC * 8;

    // prep: LDS inverse (blocks 0..1, hidden under converts) + grid-stride converts
    k_prep<<<PREP_BLOCKS, 256, 0, stream>>>(x, w_in, w1, w2, w_out, wa, wx,
                                            xb, wib, w1b, w2b, wob, wgb,
                                            v_re, v_im, h0_re, h0_im, vinv, h0c);

    // in-proj: xb(f16) @ w_in^T (64x128 tile, split-K=8, f16 partials) — 512 blocks
    {
        dim3 g(DIMC/128, NTOK/64, 8);
        k_gemmT<64,128,1><<<g, 256, 0, stream>>>(xb, wib, pbuf, nullptr, DIMC, VOCABC, VOCABC/8, NTOK*DIMC,
                                                 nullptr, nullptr);
    }

    for (int d = 0; d < DEPTHC; ++d){
        float* cur = (d == 0) ? h1 : h3;   // layer input (reduced), residual for siout
        float* hb  = h2;                    // sio+residual out
        const float* redBias = (d == 0) ? b_in : (b2 + (d-1)*DIMC);
        const float* redRes  = (d == 0) ? nullptr : h2;
        // fused: split-K reduce + residual + write h + LN1 -> z (f16)
        k_ln1<<<NTOK, 128, 0, stream>>>(pbuf, redBias, redRes,
                                        ln1_g + d*DIMC, ln1_b + d*DIMC, zb, cur, NTOK*DIMC);
        // gate projections via MFMA + fused nonlinearity -> a_t, xc  (grid 32 blocks)
        {
            dim3 g(1, NTOK/32, 1);
            k_gemmT<32,128,3><<<g, 256, 0, stream>>>(zb, wgb + (size_t)d*128*DIMC, nullptr, nullptr,
                                                     128, DIMC, DIMC, 0, a_t, xc);
        }
        k_scan<<<BC*INNERC, 64, 0, stream>>>(a_t, xc, vinv + d*INNERC*INNERC, h0c + d*INNERC, ev);
        k_siout_ln<<<NTOK, 128, 0, stream>>>(ev, xc, v_re + d*INNERC*INNERC, v_im + d*INNERC*INNERC,
                                             w_ol + (size_t)d*DIMC*INNERC, cur,
                                             ln2_g + d*DIMC, ln2_b + d*DIMC, hb, zb);
        // FFN1: 64x128 tile, silu fused, f16 out
        {
            dim3 g(FFC/128, NTOK/64, 1);
            k_gemmT<64,128,2><<<g, 256, 0, stream>>>(zb, w1b + (size_t)d*FFC*DIMC, ffb, b1 + d*FFC,
                                                     FFC, DIMC, DIMC, 0, nullptr, nullptr);
        }
        // FFN2: 64x128 tile, split-K=8, f16 partials
        {
            dim3 g(DIMC/128, NTOK/64, 8);
            k_gemmT<64,128,1><<<g, 256, 0, stream>>>(ffb, w2b + (size_t)d*DIMC*FFC, pbuf, nullptr,
                                                     DIMC, FFC, FFC/8, NTOK*DIMC, nullptr, nullptr);
        }
    }
    // final: reduce + residual + LN -> zb (f16)
    k_ln1<<<NTOK, 128, 0, stream>>>(pbuf, b2 + (DEPTHC-1)*DIMC, h2, lnl_g, lnl_b, zb, nullptr, NTOK*DIMC);
    // out = zb @ w_out^T + b_out  (128x128 tile)
    {
        dim3 g(VOCABC/128, NTOK/128, 1);
        k_gemmT<128,128,0><<<g, 256, 0, stream>>>(zb, wob, (float*)d_out, b_out, VOCABC, DIMC, DIMC, 0,
                                                  nullptr, nullptr);
    }
    (void)in_sizes; (void)n_in; (void)out_size; (void)ws_size;
}